// Round 2
// baseline (222.958 us; speedup 1.0000x reference)
//
#include <hip/hip_runtime.h>
#include <stdint.h>

typedef unsigned short ushort_t;
typedef __bf16 bf16x8 __attribute__((ext_vector_type(8)));
typedef float floatx4 __attribute__((ext_vector_type(4)));

#define B_   8
#define S_   1024
#define D_   768
#define H_   12
#define M_   (B_ * S_)   // 8192
#define N3_  (3 * D_)    // 2304
#define QK_  1536        // qk buffer row stride (Q at +0, K at +768)

static __device__ __forceinline__ void gl_lds16(const void* g, void* l) {
  __builtin_amdgcn_global_load_lds((const __attribute__((address_space(1))) void*)g,
                                   (__attribute__((address_space(3))) void*)l,
                                   16, 0, 0);
}

static __device__ __forceinline__ ushort_t f2bf(float f) {
  __bf16 h = (__bf16)f;
  return __builtin_bit_cast(unsigned short, h);
}

static __device__ __forceinline__ void store_out(ushort_t* p, float v) { *p = f2bf(v); }
static __device__ __forceinline__ void store_out(float* p, float v) { *p = v; }

// ---------------------------------------------------------------------------
// Merged prep: x f32->bf16 (blocks 0..24575), w_qkv transpose (next 1728),
// w_proj transpose (next 576). One dispatch instead of three. (unchanged)
// ---------------------------------------------------------------------------
static __device__ __forceinline__ void transpose_tile(const float* __restrict__ W,
                                                      ushort_t* __restrict__ Wt,
                                                      int K, int N, int bx, int by,
                                                      int t) {
  __shared__ float tile[32][33];
  const int n0 = bx * 32, k0 = by * 32;
  const int tx = t & 31, ty = t >> 5;
#pragma unroll
  for (int i = 0; i < 4; ++i)
    tile[ty + i * 8][tx] = W[(size_t)(k0 + ty + i * 8) * N + n0 + tx];
  __syncthreads();
#pragma unroll
  for (int i = 0; i < 4; ++i)
    Wt[(size_t)(n0 + ty + i * 8) * K + k0 + tx] = f2bf(tile[tx][ty + i * 8]);
}

__global__ __launch_bounds__(256) void prep_kernel(const float* __restrict__ x,
                                                   ushort_t* __restrict__ xb,
                                                   const float* __restrict__ w_qkv,
                                                   ushort_t* __restrict__ wqkvt,
                                                   const float* __restrict__ w_proj,
                                                   ushort_t* __restrict__ wprojt) {
  const int gb = blockIdx.x, t = threadIdx.x;
  if (gb < 24576) {
    const int i = gb * 256 + t;
    xb[i] = f2bf(x[i]);
  } else if (gb < 24576 + 1728) {
    const int lb = gb - 24576;                 // 72 x 24 tiles
    transpose_tile(w_qkv, wqkvt, D_, N3_, lb % 72, lb / 72, t);
  } else {
    const int lb = gb - 24576 - 1728;          // 24 x 24 tiles
    transpose_tile(w_proj, wprojt, D_, D_, lb % 24, lb / 24, t);
  }
}

// ---------------------------------------------------------------------------
// GEMM 256x256, BK=64, 512 threads (8 waves, 2M x 4N), deep-pipelined:
//   - 4 phases per K-tile, 2-deep LDS dbuf (128 KB), 1 half-tile staged/phase
//   - counted s_waitcnt vmcnt(2) at each K-tile boundary (never 0 mid-loop)
//   - T2 XOR-swizzle (slot ^= row&7) via pre-swizzled global source addrs
//   - __builtin_amdgcn_s_barrier (no compiler vmcnt(0) drain), s_setprio(1)
//     around MFMA clusters, bijective XCD swizzle of blockIdx
// Choreography (race-freedom by construction):
//   kt's LDS reads: A-h0/h1 at ph0 (lo 64 rows of each wm-half) and ph2 (hi),
//   B-h0/h1 at ph0 (ni0-1) and ph1 (ni2-3). Stage targets & earliest-free:
//   ph0: A-h1(kt+1)  [occupant A(kt-1)-h1 last read ph2 of kt-1, 2 phases ago]
//   ph1: B-h0(kt+1)  [occupant last read ph0 of kt-1, 4+ phases ago]
//   ph2: B-h1(kt+1)  [occupant last read ph1 of kt-1, 4+ phases ago]
//   ph3: A-h0(kt+2)  [occupant A(kt)-h0 last read THIS kt's ph0, barriers ago]
//   Boundary vmcnt(2) leaves only A-h0(kt+2)'s 2 loads in flight => all of
//   kt+1's half-tiles landed (in-order vmcnt retirement) before its ph0.
// ---------------------------------------------------------------------------
static __device__ __forceinline__ void stage_half(const ushort_t* __restrict__ gt,
                                                  int k0, ushort_t* lds, int h,
                                                  int wave, int srl, int scol) {
  const int rb0 = h * 128;
  gl_lds16(gt + (size_t)(rb0 + srl) * 768 + k0 + scol, lds + (rb0 + wave * 8) * 64);
  const int rb1 = h * 128 + 64;
  gl_lds16(gt + (size_t)(rb1 + srl) * 768 + k0 + scol, lds + (rb1 + wave * 8) * 64);
}

template <typename OutT, bool SPLITV>
__global__ __launch_bounds__(512, 2) void gemm256(const ushort_t* __restrict__ A,
                                                  const ushort_t* __restrict__ Bt,
                                                  const float* __restrict__ bias,
                                                  OutT* __restrict__ C, int CN,
                                                  ushort_t* __restrict__ vt,
                                                  int NBX, int CHUNK) {
  __shared__ __align__(16) ushort_t As[2][256 * 64];   // 64 KB
  __shared__ __align__(16) ushort_t Bs[2][256 * 64];   // 64 KB

  const int t = threadIdx.x;
  const int wave = t >> 6, lane = t & 63;
  const int quad = lane >> 4, l15 = lane & 15;
  const int wm = wave >> 2, wn = wave & 3;             // 2 x 4 wave grid

  // XCD-aware bijective swizzle (grid % 8 == 0 guaranteed by caller)
  const int g = blockIdx.x;
  const int swz = (g & 7) * CHUNK + (g >> 3);
  const int bx = swz % NBX, by = swz / NBX;
  const int m0 = by * 256, n0 = bx * 256;

  // staging constants: thread covers row srl (0..63) of a 64-row chunk;
  // dest slot = lane&7 (linear), source col16 = (lane&7)^(lane>>3) so that
  // physical slot s of row r holds logical col16 s^(r&7)  (r&7 == lane>>3).
  const int srl  = wave * 8 + (lane >> 3);
  const int scol = ((lane & 7) ^ (lane >> 3)) * 8;

  // ds_read swizzle: frag row & 7 == l15 & 7 for all our rows
  const int rsw = l15 & 7;
  int slotk[2];
  slotk[0] = ((0 * 4 + quad) ^ rsw) * 8;
  slotk[1] = ((1 * 4 + quad) ^ rsw) * 8;

  const int arow = wm * 128 + l15;   // + mi*16 (+64 for hi half)
  const int brow = wn * 64 + l15;    // + ni*16

  const ushort_t* At  = A + (size_t)m0 * 768;
  const ushort_t* Bte = Bt + (size_t)n0 * 768;

  floatx4 acc[8][4];
#pragma unroll
  for (int i = 0; i < 8; ++i)
#pragma unroll
    for (int j = 0; j < 4; ++j) acc[i][j] = (floatx4)0.0f;

  // prologue: A0(0) A1(0) B0(0) B1(0) A0(1); allow A0(1) to stay in flight
  stage_half(At, 0, As[0], 0, wave, srl, scol);
  stage_half(At, 0, As[0], 1, wave, srl, scol);
  stage_half(Bte, 0, Bs[0], 0, wave, srl, scol);
  stage_half(Bte, 0, Bs[0], 1, wave, srl, scol);
  stage_half(At, 64, As[1], 0, wave, srl, scol);
  asm volatile("s_waitcnt vmcnt(2)" ::: "memory");
  __builtin_amdgcn_s_barrier();

  bf16x8 af[4][2], bf2[4][2];

  for (int kt = 0; kt < 12; ++kt) {
    const int k0 = kt * 64;
    const ushort_t* Ab = As[kt & 1];
    const ushort_t* Bb = Bs[kt & 1];
    ushort_t* An  = As[(kt + 1) & 1];
    ushort_t* Bn  = Bs[(kt + 1) & 1];
    ushort_t* Af2 = As[kt & 1];               // (kt+2) target: same parity
    const bool p1 = (kt + 1) < 12;
    const bool p2 = (kt + 2) < 12;

    // ---- ph0: read A-lo (8) + B-lo (4); stage A-h1(kt+1); MFMA Q(lo,lo)
#pragma unroll
    for (int mi = 0; mi < 4; ++mi)
#pragma unroll
      for (int kb = 0; kb < 2; ++kb)
        af[mi][kb] = *(const bf16x8*)(Ab + (arow + mi * 16) * 64 + slotk[kb]);
#pragma unroll
    for (int ni = 0; ni < 2; ++ni)
#pragma unroll
      for (int kb = 0; kb < 2; ++kb)
        bf2[ni][kb] = *(const bf16x8*)(Bb + (brow + ni * 16) * 64 + slotk[kb]);
    if (p1) stage_half(At, k0 + 64, An, 1, wave, srl, scol);
    __builtin_amdgcn_s_barrier();
    __builtin_amdgcn_s_setprio(1);
#pragma unroll
    for (int ni = 0; ni < 2; ++ni)
#pragma unroll
      for (int kb = 0; kb < 2; ++kb)
#pragma unroll
        for (int mi = 0; mi < 4; ++mi)
          acc[mi][ni] = __builtin_amdgcn_mfma_f32_16x16x32_bf16(af[mi][kb], bf2[ni][kb], acc[mi][ni], 0, 0, 0);
    __builtin_amdgcn_s_setprio(0);
    __builtin_amdgcn_s_barrier();

    // ---- ph1: read B-hi (4); stage B-h0(kt+1); MFMA Q(lo,hi)
#pragma unroll
    for (int ni = 0; ni < 2; ++ni)
#pragma unroll
      for (int kb = 0; kb < 2; ++kb)
        bf2[2 + ni][kb] = *(const bf16x8*)(Bb + (brow + (2 + ni) * 16) * 64 + slotk[kb]);
    if (p1) stage_half(Bte, k0 + 64, Bn, 0, wave, srl, scol);
    __builtin_amdgcn_s_barrier();
    __builtin_amdgcn_s_setprio(1);
#pragma unroll
    for (int ni = 0; ni < 2; ++ni)
#pragma unroll
      for (int kb = 0; kb < 2; ++kb)
#pragma unroll
        for (int mi = 0; mi < 4; ++mi)
          acc[mi][2 + ni] = __builtin_amdgcn_mfma_f32_16x16x32_bf16(af[mi][kb], bf2[2 + ni][kb], acc[mi][2 + ni], 0, 0, 0);
    __builtin_amdgcn_s_setprio(0);
    __builtin_amdgcn_s_barrier();

    // ---- ph2: read A-hi (8, overwrite af); stage B-h1(kt+1); MFMA Q(hi,lo)
#pragma unroll
    for (int mi = 0; mi < 4; ++mi)
#pragma unroll
      for (int kb = 0; kb < 2; ++kb)
        af[mi][kb] = *(const bf16x8*)(Ab + (arow + 64 + mi * 16) * 64 + slotk[kb]);
    if (p1) stage_half(Bte, k0 + 64, Bn, 1, wave, srl, scol);
    __builtin_amdgcn_s_barrier();
    __builtin_amdgcn_s_setprio(1);
#pragma unroll
    for (int ni = 0; ni < 2; ++ni)
#pragma unroll
      for (int kb = 0; kb < 2; ++kb)
#pragma unroll
        for (int mi = 0; mi < 4; ++mi)
          acc[4 + mi][ni] = __builtin_amdgcn_mfma_f32_16x16x32_bf16(af[mi][kb], bf2[ni][kb], acc[4 + mi][ni], 0, 0, 0);
    __builtin_amdgcn_s_setprio(0);
    __builtin_amdgcn_s_barrier();

    // ---- ph3: stage A-h0(kt+2); MFMA Q(hi,hi); counted boundary vmcnt
    if (p2) stage_half(At, k0 + 128, Af2, 0, wave, srl, scol);
    __builtin_amdgcn_s_barrier();
    __builtin_amdgcn_s_setprio(1);
#pragma unroll
    for (int ni = 0; ni < 2; ++ni)
#pragma unroll
      for (int kb = 0; kb < 2; ++kb)
#pragma unroll
        for (int mi = 0; mi < 4; ++mi)
          acc[4 + mi][2 + ni] = __builtin_amdgcn_mfma_f32_16x16x32_bf16(af[mi][kb], bf2[2 + ni][kb], acc[4 + mi][2 + ni], 0, 0, 0);
    __builtin_amdgcn_s_setprio(0);
    if (p2) asm volatile("s_waitcnt vmcnt(2)" ::: "memory");
    else    asm volatile("s_waitcnt vmcnt(0)" ::: "memory");
    __builtin_amdgcn_s_barrier();
  }

  // epilogue
#pragma unroll
  for (int ni = 0; ni < 4; ++ni) {
    const int colb = n0 + wn * 64 + ni * 16;     // wave-uniform
    const float bb = bias[colb + l15];
    if (SPLITV && n0 >= 1536) {
      // whole block is V (n0 in {1536,1792,2048}); one head per wn strip
      const int hh = ((n0 - 1536) >> 6) + wn;
      const int d  = ni * 16 + l15;
      const int bh = (m0 >> 10) * H_ + hh;
      ushort_t* vrow = vt + ((size_t)bh * 64 + d) * 1024 +
                       (m0 & 1023) + wm * 128 + quad * 4;
#pragma unroll
      for (int mi = 0; mi < 8; ++mi) {
        ushort4 pk;
        pk.x = f2bf(acc[mi][ni][0] + bb);
        pk.y = f2bf(acc[mi][ni][1] + bb);
        pk.z = f2bf(acc[mi][ni][2] + bb);
        pk.w = f2bf(acc[mi][ni][3] + bb);
        *(ushort4*)(vrow + mi * 16) = pk;
      }
    } else {
      const int col = colb + l15;
#pragma unroll
      for (int mi = 0; mi < 8; ++mi)
#pragma unroll
        for (int r = 0; r < 4; ++r) {
          const int row = m0 + wm * 128 + mi * 16 + quad * 4 + r;
          store_out(&C[(size_t)row * CN + col], acc[mi][ni][r] + bb);
        }
    }
  }
}

// ---------------------------------------------------------------------------
// Flash attention v4 (unchanged this round): 128 q-rows/block, 64-wide kv
// tiles, XOR-swizzled LDS, XCD-swizzled grid, fixed-max softmax.
// ---------------------------------------------------------------------------
__global__ __launch_bounds__(256) void attn_kernel(const ushort_t* __restrict__ qk,
                                                   const ushort_t* __restrict__ vt,
                                                   ushort_t* __restrict__ o) {
  __shared__ __align__(16) ushort_t Qs[128 * 64];   // 16 KB
  __shared__ __align__(16) ushort_t Ks[64 * 64];    //  8 KB
  __shared__ __align__(16) ushort_t Vts[64 * 64];   //  8 KB (V^T, swizzled)
  __shared__ __align__(16) ushort_t Ps[128 * 72];   // 18 KB

  const int t = threadIdx.x;
  const int wave = t >> 6, lane = t & 63;
  const int quad = lane >> 4, l15 = lane & 15;

  // XCD swizzle: 768 blocks; xcd=g&7 gets 12 contiguous bh, 8 q-tiles each.
  const int g = blockIdx.x;
  const int xcd = g & 7, gi = g >> 3;          // gi in 0..95
  const int bh = xcd * 12 + (gi >> 3);         // 0..95
  const int q0 = (gi & 7) * 128;
  const int h = bh % H_;
  const int bS = (bh / H_) * S_;
  const ushort_t* vbase = vt + (size_t)bh * 64 * 1024;

  // stage Q (once): 128x64 = 1024 granules of 16B, swizzled source
#pragma unroll
  for (int c = 0; c < 4; ++c) {
    const int i0 = c * 256 + wave * 64;  // wave-uniform
    const int i = i0 + lane;
    const int row = i >> 3, sg = (i & 7) ^ (row & 7);
    gl_lds16(qk + (size_t)(bS + q0 + row) * QK_ + h * 64 + sg * 8, Qs + i0 * 8);
  }
  __syncthreads();

  bf16x8 qf[2][2];
#pragma unroll
  for (int mi = 0; mi < 2; ++mi)
#pragma unroll
    for (int kb = 0; kb < 2; ++kb)
      qf[mi][kb] = *(const bf16x8*)(Qs + (wave * 32 + mi * 16 + l15) * 64 +
                                    (((kb * 4 + quad) ^ (l15 & 7)) * 8));

  floatx4 oa[2][4];
#pragma unroll
  for (int mi = 0; mi < 2; ++mi)
#pragma unroll
    for (int d = 0; d < 4; ++d) oa[mi][d] = (floatx4)0.0f;
  float lsum[2][4] = {{0.f, 0.f, 0.f, 0.f}, {0.f, 0.f, 0.f, 0.f}};

  for (int kv0 = 0; kv0 < S_; kv0 += 64) {
    // stage K and V^T tiles (512 granules each), swizzled source
#pragma unroll
    for (int c = 0; c < 2; ++c) {
      const int i0 = c * 256 + wave * 64;
      const int i = i0 + lane;
      const int row = i >> 3, sg = (i & 7) ^ (row & 7);
      gl_lds16(qk + (size_t)(bS + kv0 + row) * QK_ + 768 + h * 64 + sg * 8,
               Ks + i0 * 8);
      gl_lds16(vbase + (size_t)row * 1024 + kv0 + sg * 8, Vts + i0 * 8);
    }
    __syncthreads();

    // S = Q K^T : 2x4 blocks of 16x16, 16 MFMA
    floatx4 sa[2][4];
#pragma unroll
    for (int mi = 0; mi < 2; ++mi)
#pragma unroll
      for (int ni = 0; ni < 4; ++ni) sa[mi][ni] = (floatx4)0.0f;
#pragma unroll
    for (int ni = 0; ni < 4; ++ni)
#pragma unroll
      for (int kb = 0; kb < 2; ++kb) {
        const bf16x8 kf = *(const bf16x8*)(Ks + (ni * 16 + l15) * 64 +
                                           (((kb * 4 + quad) ^ (l15 & 7)) * 8));
#pragma unroll
        for (int mi = 0; mi < 2; ++mi)
          sa[mi][ni] = __builtin_amdgcn_mfma_f32_16x16x32_bf16(qf[mi][kb], kf, sa[mi][ni], 0, 0, 0);
      }

    // fixed-max softmax: p = exp(s*0.125 - 16); lane-local l accumulation
#pragma unroll
    for (int mi = 0; mi < 2; ++mi)
#pragma unroll
      for (int r = 0; r < 4; ++r) {
        float psum = 0.0f;
#pragma unroll
        for (int ni = 0; ni < 4; ++ni) {
          const float p = __expf(fmaf(sa[mi][ni][r], 0.125f, -16.0f));
          psum += p;
          Ps[(wave * 32 + mi * 16 + quad * 4 + r) * 72 + ni * 16 + l15] = f2bf(p);
        }
        lsum[mi][r] += psum;
      }
    // Ps rows [wave*32, wave*32+32) are wave-private; lgkmcnt orders wr->rd.

    // O += P V : 16 MFMA
#pragma unroll
    for (int kb = 0; kb < 2; ++kb) {
      bf16x8 vf[4];
#pragma unroll
      for (int dt = 0; dt < 4; ++dt)
        vf[dt] = *(const bf16x8*)(Vts + (dt * 16 + l15) * 64 +
                                  (((kb * 4 + quad) ^ (l15 & 7)) * 8));
#pragma unroll
      for (int mi = 0; mi < 2; ++mi) {
        const bf16x8 pf = *(const bf16x8*)(Ps + (wave * 32 + mi * 16 + l15) * 72 +
                                           kb * 32 + quad * 8);
#pragma unroll
        for (int dt = 0; dt < 4; ++dt)
          oa[mi][dt] = __builtin_amdgcn_mfma_f32_16x16x32_bf16(pf, vf[dt], oa[mi][dt], 0, 0, 0);
      }
    }
    __syncthreads();
  }

  // one-time l reduction across the 16-lane row groups
#pragma unroll
  for (int mi = 0; mi < 2; ++mi)
#pragma unroll
    for (int r = 0; r < 4; ++r) {
#pragma unroll
      for (int off = 8; off >= 1; off >>= 1)
        lsum[mi][r] += __shfl_xor(lsum[mi][r], off, 64);
    }

  // epilogue: normalize and store [B,S,H*Hd] bf16
#pragma unroll
  for (int mi = 0; mi < 2; ++mi)
#pragma unroll
    for (int dt = 0; dt < 4; ++dt)
#pragma unroll
      for (int r = 0; r < 4; ++r) {
        const int q = q0 + wave * 32 + mi * 16 + quad * 4 + r;
        o[(size_t)(bS + q) * D_ + h * 64 + dt * 16 + l15] =
            f2bf(oa[mi][dt][r] / lsum[mi][r]);
      }
}

// ---------------------------------------------------------------------------
extern "C" void kernel_launch(void* const* d_in, const int* in_sizes, int n_in,
                              void* d_out, int out_size, void* d_ws, size_t ws_size,
                              hipStream_t stream) {
  const float* x      = (const float*)d_in[0];  // [8192, 768] f32
  const float* w_qkv  = (const float*)d_in[1];  // [768, 2304] f32
  const float* b_qkv  = (const float*)d_in[2];  // [2304] f32
  const float* w_proj = (const float*)d_in[3];  // [768, 768] f32
  const float* b_proj = (const float*)d_in[4];  // [768] f32
  float* out = (float*)d_out;                   // [8192, 768] f32

  ushort_t* xb = (ushort_t*)d_out;  // x as bf16, dead before proj GEMM writes

  // ws layout (bf16 units), 55.05 MB total (fault-free footprint r3-r9)
  ushort_t* vtb    = (ushort_t*)d_ws;              // [96*64, 1024] 12.58 MB
  ushort_t* wqkvt  = vtb + (size_t)96 * 64 * 1024; // [2304, 768]    3.54 MB
  ushort_t* wprojt = wqkvt + (size_t)N3_ * D_;     // [768, 768]     1.18 MB
  ushort_t* qkb    = wprojt + (size_t)D_ * D_;     // [8192, 1536]  25.17 MB
  ushort_t* attnb  = qkb + (size_t)M_ * QK_;       // [8192, 768]   12.58 MB

  prep_kernel<<<24576 + 1728 + 576, 256, 0, stream>>>(x, xb, w_qkv, wqkvt,
                                                      w_proj, wprojt);
  // QKV: M=8192, N=2304 -> 32 x 9 = 288 blocks (288 % 8 == 0)
  gemm256<ushort_t, true><<<288, 512, 0, stream>>>(xb, wqkvt, b_qkv, qkb, QK_,
                                                   vtb, 9, 36);
  attn_kernel<<<dim3(768), 256, 0, stream>>>(qkb, vtb, attnb);
  // proj: M=8192, N=768 -> 32 x 3 = 96 blocks (96 % 8 == 0)
  gemm256<float, false><<<96, 512, 0, stream>>>(attnb, wprojt, b_proj, out, D_,
                                                nullptr, 3, 12);
}

// Round 3
// 199.056 us; speedup vs baseline: 1.1201x; 1.1201x over previous
//
#include <hip/hip_runtime.h>
#include <stdint.h>

typedef unsigned short ushort_t;
typedef __bf16 bf16x8 __attribute__((ext_vector_type(8)));
typedef float floatx4 __attribute__((ext_vector_type(4)));

#define B_   8
#define S_   1024
#define D_   768
#define H_   12
#define M_   (B_ * S_)   // 8192
#define N3_  (3 * D_)    // 2304
#define QK_  1536        // qk buffer row stride (Q at +0, K at +768)

static __device__ __forceinline__ void gl_lds16(const void* g, void* l) {
  __builtin_amdgcn_global_load_lds((const __attribute__((address_space(1))) void*)g,
                                   (__attribute__((address_space(3))) void*)l,
                                   16, 0, 0);
}

static __device__ __forceinline__ ushort_t f2bf(float f) {
  __bf16 h = (__bf16)f;
  return __builtin_bit_cast(unsigned short, h);
}

static __device__ __forceinline__ void store_out(ushort_t* p, float v) { *p = f2bf(v); }
static __device__ __forceinline__ void store_out(float* p, float v) { *p = v; }

// ---------------------------------------------------------------------------
// Merged prep: x f32->bf16 (blocks 0..24575), w_qkv transpose (next 1728),
// w_proj transpose (next 576). (unchanged)
// ---------------------------------------------------------------------------
static __device__ __forceinline__ void transpose_tile(const float* __restrict__ W,
                                                      ushort_t* __restrict__ Wt,
                                                      int K, int N, int bx, int by,
                                                      int t) {
  __shared__ float tile[32][33];
  const int n0 = bx * 32, k0 = by * 32;
  const int tx = t & 31, ty = t >> 5;
#pragma unroll
  for (int i = 0; i < 4; ++i)
    tile[ty + i * 8][tx] = W[(size_t)(k0 + ty + i * 8) * N + n0 + tx];
  __syncthreads();
#pragma unroll
  for (int i = 0; i < 4; ++i)
    Wt[(size_t)(n0 + ty + i * 8) * K + k0 + tx] = f2bf(tile[tx][ty + i * 8]);
}

__global__ __launch_bounds__(256) void prep_kernel(const float* __restrict__ x,
                                                   ushort_t* __restrict__ xb,
                                                   const float* __restrict__ w_qkv,
                                                   ushort_t* __restrict__ wqkvt,
                                                   const float* __restrict__ w_proj,
                                                   ushort_t* __restrict__ wprojt) {
  const int gb = blockIdx.x, t = threadIdx.x;
  if (gb < 24576) {
    const int i = gb * 256 + t;
    xb[i] = f2bf(x[i]);
  } else if (gb < 24576 + 1728) {
    const int lb = gb - 24576;                 // 72 x 24 tiles
    transpose_tile(w_qkv, wqkvt, D_, N3_, lb % 72, lb / 72, t);
  } else {
    const int lb = gb - 24576 - 1728;          // 24 x 24 tiles
    transpose_tile(w_proj, wprojt, D_, D_, lb % 24, lb / 24, t);
  }
}

// ---------------------------------------------------------------------------
// GEMM 128x128, BK=64, 256 threads (4 waves, 2M x 2N), pipelined 2-phase:
//   - double-buffered LDS (64 KB -> 2 blocks/CU), stage(kt+1) issued BEFORE
//     compute(kt); single vmcnt(0)+s_barrier per K-tile at the END, so the
//     drain is covered by 16 ds_read_b128 + 32 MFMA (T3/T4 minimum template)
//   - BK=64 XOR-swizzled LDS (row=128B: bank = f(slot) only -> conflict-free,
//     verified r2: SQ_LDS_BANK_CONFLICT = 0) via pre-swizzled global source
//   - bijective XCD swizzle of linear blockIdx (grids 1152, 384: both %8==0)
// Race audit: stage(kt+1) targets the buffer last read at kt-1; all waves
// passed kt-1's end barrier -> WAR safe. vmcnt(0) before each barrier ->
// RAW safe. All branches uniform in kt -> no barrier divergence.
// ---------------------------------------------------------------------------
template <typename OutT, bool SPLITV>
__global__ __launch_bounds__(256, 2) void gemm128(const ushort_t* __restrict__ A,
                                                  const ushort_t* __restrict__ Bt,
                                                  const float* __restrict__ bias,
                                                  OutT* __restrict__ C, int CN,
                                                  ushort_t* __restrict__ vt,
                                                  int NBX, int CHUNK) {
  __shared__ __align__(16) ushort_t As[2][128 * 64];   // 32 KB
  __shared__ __align__(16) ushort_t Bs[2][128 * 64];   // 32 KB

  const int t = threadIdx.x;
  const int wave = t >> 6, lane = t & 63;
  const int quad = lane >> 4, l15 = lane & 15;
  const int wm = wave >> 1, wn = wave & 1;             // 2 x 2 wave grid

  // XCD-aware bijective swizzle (grid % 8 == 0 guaranteed by caller)
  const int g = blockIdx.x;
  const int swz = (g & 7) * CHUNK + (g >> 3);
  const int bx = swz % NBX, by = swz / NBX;
  const int m0 = by * 128, n0 = bx * 128;

  // staging: issue c covers rows c*32..c*32+31; thread -> row c*32+wave*8+
  // (lane>>3), physical slot lane&7. Slot s of row r holds logical k-group
  // s^(r&7); r&7 == (lane>>3)&7, so source col16 = (lane&7)^((lane>>3)&7).
  const int rsub = wave * 8 + (lane >> 3);
  const int scol = ((lane & 7) ^ ((lane >> 3) & 7)) * 8;

  // frag reads: row = base+l15 (base mult of 16) -> r&7 == l15&7
  const int rsw = l15 & 7;
  const int slot0 = ((0 * 4 + quad) ^ rsw) * 8;        // kb=0
  const int slot1 = ((1 * 4 + quad) ^ rsw) * 8;        // kb=1

  const int arow = wm * 64 + l15;
  const int brow = wn * 64 + l15;

  const ushort_t* At  = A + (size_t)m0 * 768;
  const ushort_t* Bte = Bt + (size_t)n0 * 768;

  floatx4 acc[4][4];
#pragma unroll
  for (int i = 0; i < 4; ++i)
#pragma unroll
    for (int j = 0; j < 4; ++j) acc[i][j] = (floatx4)0.0f;

  // prologue: stage K-tile 0 into buffer 0, drain, barrier
#pragma unroll
  for (int c = 0; c < 4; ++c) {
    gl_lds16(At + (size_t)(c * 32 + rsub) * 768 + scol,
             &As[0][(c * 32 + wave * 8) * 64]);
    gl_lds16(Bte + (size_t)(c * 32 + rsub) * 768 + scol,
             &Bs[0][(c * 32 + wave * 8) * 64]);
  }
  asm volatile("s_waitcnt vmcnt(0)" ::: "memory");
  __builtin_amdgcn_s_barrier();

#pragma unroll
  for (int kt = 0; kt < 12; ++kt) {
    const ushort_t* Ab = As[kt & 1];
    const ushort_t* Bb = Bs[kt & 1];

    // issue next tile's staging FIRST (lands during compute below)
    if (kt + 1 < 12) {
      const int k1 = (kt + 1) * 64;
      ushort_t* An = As[(kt + 1) & 1];
      ushort_t* Bn = Bs[(kt + 1) & 1];
#pragma unroll
      for (int c = 0; c < 4; ++c) {
        gl_lds16(At + (size_t)(c * 32 + rsub) * 768 + k1 + scol,
                 An + (c * 32 + wave * 8) * 64);
        gl_lds16(Bte + (size_t)(c * 32 + rsub) * 768 + k1 + scol,
                 Bn + (c * 32 + wave * 8) * 64);
      }
    }

    // compute current tile
    bf16x8 af[4][2], bfr[4][2];
#pragma unroll
    for (int mi = 0; mi < 4; ++mi) {
      af[mi][0] = *(const bf16x8*)(Ab + (arow + mi * 16) * 64 + slot0);
      af[mi][1] = *(const bf16x8*)(Ab + (arow + mi * 16) * 64 + slot1);
    }
#pragma unroll
    for (int ni = 0; ni < 4; ++ni) {
      bfr[ni][0] = *(const bf16x8*)(Bb + (brow + ni * 16) * 64 + slot0);
      bfr[ni][1] = *(const bf16x8*)(Bb + (brow + ni * 16) * 64 + slot1);
    }
#pragma unroll
    for (int mi = 0; mi < 4; ++mi)
#pragma unroll
      for (int ni = 0; ni < 4; ++ni) {
        acc[mi][ni] = __builtin_amdgcn_mfma_f32_16x16x32_bf16(af[mi][0], bfr[ni][0], acc[mi][ni], 0, 0, 0);
        acc[mi][ni] = __builtin_amdgcn_mfma_f32_16x16x32_bf16(af[mi][1], bfr[ni][1], acc[mi][ni], 0, 0, 0);
      }

    // drain next-tile loads (covered by the 16 ds_read + 32 MFMA above)
    asm volatile("s_waitcnt vmcnt(0)" ::: "memory");
    __builtin_amdgcn_s_barrier();
  }

  // epilogue (verbatim from the r0-verified kernel)
#pragma unroll
  for (int ni = 0; ni < 4; ++ni) {
    const int colb = n0 + wn * 64 + ni * 16;   // wave-uniform
    const int col = colb + l15;
    const float bb = bias[col];
    if (SPLITV && colb >= 1536) {
      const int hh = (colb - 1536) >> 6;
      const int d  = ((colb - 1536) & 63) + l15;
      const int bh = (m0 >> 10) * H_ + hh;
      ushort_t* vrow = vt + ((size_t)bh * 64 + d) * 1024 +
                       (m0 & 1023) + wm * 64 + quad * 4;
#pragma unroll
      for (int mi = 0; mi < 4; ++mi) {
        ushort4 pk;
        pk.x = f2bf(acc[mi][ni][0] + bb);
        pk.y = f2bf(acc[mi][ni][1] + bb);
        pk.z = f2bf(acc[mi][ni][2] + bb);
        pk.w = f2bf(acc[mi][ni][3] + bb);
        *(ushort4*)(vrow + mi * 16) = pk;
      }
    } else {
#pragma unroll
      for (int mi = 0; mi < 4; ++mi) {
#pragma unroll
        for (int r = 0; r < 4; ++r) {
          const int row = m0 + wm * 64 + mi * 16 + quad * 4 + r;
          store_out(&C[(size_t)row * CN + col], acc[mi][ni][r] + bb);
        }
      }
    }
  }
}

// ---------------------------------------------------------------------------
// Flash attention v4 (unchanged this round): 128 q-rows/block, 64-wide kv
// tiles, XOR-swizzled LDS, XCD-swizzled grid, fixed-max softmax.
// ---------------------------------------------------------------------------
__global__ __launch_bounds__(256) void attn_kernel(const ushort_t* __restrict__ qk,
                                                   const ushort_t* __restrict__ vt,
                                                   ushort_t* __restrict__ o) {
  __shared__ __align__(16) ushort_t Qs[128 * 64];   // 16 KB
  __shared__ __align__(16) ushort_t Ks[64 * 64];    //  8 KB
  __shared__ __align__(16) ushort_t Vts[64 * 64];   //  8 KB (V^T, swizzled)
  __shared__ __align__(16) ushort_t Ps[128 * 72];   // 18 KB

  const int t = threadIdx.x;
  const int wave = t >> 6, lane = t & 63;
  const int quad = lane >> 4, l15 = lane & 15;

  // XCD swizzle: 768 blocks; xcd=g&7 gets 12 contiguous bh, 8 q-tiles each.
  const int g = blockIdx.x;
  const int xcd = g & 7, gi = g >> 3;          // gi in 0..95
  const int bh = xcd * 12 + (gi >> 3);         // 0..95
  const int q0 = (gi & 7) * 128;
  const int h = bh % H_;
  const int bS = (bh / H_) * S_;
  const ushort_t* vbase = vt + (size_t)bh * 64 * 1024;

  // stage Q (once): 128x64 = 1024 granules of 16B, swizzled source
#pragma unroll
  for (int c = 0; c < 4; ++c) {
    const int i0 = c * 256 + wave * 64;  // wave-uniform
    const int i = i0 + lane;
    const int row = i >> 3, sg = (i & 7) ^ (row & 7);
    gl_lds16(qk + (size_t)(bS + q0 + row) * QK_ + h * 64 + sg * 8, Qs + i0 * 8);
  }
  __syncthreads();

  bf16x8 qf[2][2];
#pragma unroll
  for (int mi = 0; mi < 2; ++mi)
#pragma unroll
    for (int kb = 0; kb < 2; ++kb)
      qf[mi][kb] = *(const bf16x8*)(Qs + (wave * 32 + mi * 16 + l15) * 64 +
                                    (((kb * 4 + quad) ^ (l15 & 7)) * 8));

  floatx4 oa[2][4];
#pragma unroll
  for (int mi = 0; mi < 2; ++mi)
#pragma unroll
    for (int d = 0; d < 4; ++d) oa[mi][d] = (floatx4)0.0f;
  float lsum[2][4] = {{0.f, 0.f, 0.f, 0.f}, {0.f, 0.f, 0.f, 0.f}};

  for (int kv0 = 0; kv0 < S_; kv0 += 64) {
    // stage K and V^T tiles (512 granules each), swizzled source
#pragma unroll
    for (int c = 0; c < 2; ++c) {
      const int i0 = c * 256 + wave * 64;
      const int i = i0 + lane;
      const int row = i >> 3, sg = (i & 7) ^ (row & 7);
      gl_lds16(qk + (size_t)(bS + kv0 + row) * QK_ + 768 + h * 64 + sg * 8,
               Ks + i0 * 8);
      gl_lds16(vbase + (size_t)row * 1024 + kv0 + sg * 8, Vts + i0 * 8);
    }
    __syncthreads();

    // S = Q K^T : 2x4 blocks of 16x16, 16 MFMA
    floatx4 sa[2][4];
#pragma unroll
    for (int mi = 0; mi < 2; ++mi)
#pragma unroll
      for (int ni = 0; ni < 4; ++ni) sa[mi][ni] = (floatx4)0.0f;
#pragma unroll
    for (int ni = 0; ni < 4; ++ni)
#pragma unroll
      for (int kb = 0; kb < 2; ++kb) {
        const bf16x8 kf = *(const bf16x8*)(Ks + (ni * 16 + l15) * 64 +
                                           (((kb * 4 + quad) ^ (l15 & 7)) * 8));
#pragma unroll
        for (int mi = 0; mi < 2; ++mi)
          sa[mi][ni] = __builtin_amdgcn_mfma_f32_16x16x32_bf16(qf[mi][kb], kf, sa[mi][ni], 0, 0, 0);
      }

    // fixed-max softmax: p = exp(s*0.125 - 16); lane-local l accumulation
#pragma unroll
    for (int mi = 0; mi < 2; ++mi)
#pragma unroll
      for (int r = 0; r < 4; ++r) {
        float psum = 0.0f;
#pragma unroll
        for (int ni = 0; ni < 4; ++ni) {
          const float p = __expf(fmaf(sa[mi][ni][r], 0.125f, -16.0f));
          psum += p;
          Ps[(wave * 32 + mi * 16 + quad * 4 + r) * 72 + ni * 16 + l15] = f2bf(p);
        }
        lsum[mi][r] += psum;
      }
    // Ps rows [wave*32, wave*32+32) are wave-private; lgkmcnt orders wr->rd.

    // O += P V : 16 MFMA
#pragma unroll
    for (int kb = 0; kb < 2; ++kb) {
      bf16x8 vf[4];
#pragma unroll
      for (int dt = 0; dt < 4; ++dt)
        vf[dt] = *(const bf16x8*)(Vts + (dt * 16 + l15) * 64 +
                                  (((kb * 4 + quad) ^ (l15 & 7)) * 8));
#pragma unroll
      for (int mi = 0; mi < 2; ++mi) {
        const bf16x8 pf = *(const bf16x8*)(Ps + (wave * 32 + mi * 16 + l15) * 72 +
                                           kb * 32 + quad * 8);
#pragma unroll
        for (int dt = 0; dt < 4; ++dt)
          oa[mi][dt] = __builtin_amdgcn_mfma_f32_16x16x32_bf16(pf, vf[dt], oa[mi][dt], 0, 0, 0);
      }
    }
    __syncthreads();
  }

  // one-time l reduction across the 16-lane row groups
#pragma unroll
  for (int mi = 0; mi < 2; ++mi)
#pragma unroll
    for (int r = 0; r < 4; ++r) {
#pragma unroll
      for (int off = 8; off >= 1; off >>= 1)
        lsum[mi][r] += __shfl_xor(lsum[mi][r], off, 64);
    }

  // epilogue: normalize and store [B,S,H*Hd] bf16
#pragma unroll
  for (int mi = 0; mi < 2; ++mi)
#pragma unroll
    for (int dt = 0; dt < 4; ++dt)
#pragma unroll
      for (int r = 0; r < 4; ++r) {
        const int q = q0 + wave * 32 + mi * 16 + quad * 4 + r;
        o[(size_t)(bS + q) * D_ + h * 64 + dt * 16 + l15] =
            f2bf(oa[mi][dt][r] / lsum[mi][r]);
      }
}

// ---------------------------------------------------------------------------
extern "C" void kernel_launch(void* const* d_in, const int* in_sizes, int n_in,
                              void* d_out, int out_size, void* d_ws, size_t ws_size,
                              hipStream_t stream) {
  const float* x      = (const float*)d_in[0];  // [8192, 768] f32
  const float* w_qkv  = (const float*)d_in[1];  // [768, 2304] f32
  const float* b_qkv  = (const float*)d_in[2];  // [2304] f32
  const float* w_proj = (const float*)d_in[3];  // [768, 768] f32
  const float* b_proj = (const float*)d_in[4];  // [768] f32
  float* out = (float*)d_out;                   // [8192, 768] f32

  ushort_t* xb = (ushort_t*)d_out;  // x as bf16, dead before proj GEMM writes

  // ws layout (bf16 units), 55.05 MB total (fault-free footprint r3-r9)
  ushort_t* vtb    = (ushort_t*)d_ws;              // [96*64, 1024] 12.58 MB
  ushort_t* wqkvt  = vtb + (size_t)96 * 64 * 1024; // [2304, 768]    3.54 MB
  ushort_t* wprojt = wqkvt + (size_t)N3_ * D_;     // [768, 768]     1.18 MB
  ushort_t* qkb    = wprojt + (size_t)D_ * D_;     // [8192, 1536]  25.17 MB
  ushort_t* attnb  = qkb + (size_t)M_ * QK_;       // [8192, 768]   12.58 MB

  prep_kernel<<<24576 + 1728 + 576, 256, 0, stream>>>(x, xb, w_qkv, wqkvt,
                                                      w_proj, wprojt);
  // QKV: M=8192, N=2304 -> 64 x 18 = 1152 blocks (1152 = 8*144)
  gemm128<ushort_t, true><<<1152, 256, 0, stream>>>(xb, wqkvt, b_qkv, qkb, QK_,
                                                    vtb, 18, 144);
  attn_kernel<<<dim3(768), 256, 0, stream>>>(qkb, vtb, attnb);
  // proj: M=8192, N=768 -> 64 x 6 = 384 blocks (384 = 8*48)
  gemm128<float, false><<<384, 256, 0, stream>>>(attnb, wprojt, b_proj, out, D_,
                                                 nullptr, 6, 48);
}